// Round 1
// baseline (1141.210 us; speedup 1.0000x reference)
//
#include <hip/hip_runtime.h>
#include <hip/hip_bf16.h>
#include <cstdint>
#include <cstddef>

#define NTOK 16384   // B*L = 4*4096
#define DDIM 1024
#define NEXP 8

typedef __attribute__((ext_vector_type(8))) short bf16x8;
typedef __attribute__((ext_vector_type(4))) float f32x4;

__device__ __forceinline__ unsigned short f2bf(float f) {
  union { float f; unsigned u; } c; c.f = f;
  unsigned r = (c.u + 0x7FFFu + ((c.u >> 16) & 1u)) >> 16;  // RNE
  return (unsigned short)r;
}

__device__ __forceinline__ float gelu_exact(float v) {
  return 0.5f * v * (1.0f + erff(v * 0.70710678118654752440f));
}

// direct global->LDS async copy, 16B per lane. LDS dest must be linear
// (wave-uniform base + lane*16); source address is per-lane.
#define GL2LDS(gp, lp) __builtin_amdgcn_global_load_lds( \
    (__attribute__((address_space(1))) void*)(gp),       \
    (__attribute__((address_space(3))) void*)(lp), 16, 0, 0)

// ---------------- cast fp32 -> bf16, 4 elems/thread ----------------
__global__ void cast_k(const float* __restrict__ src, unsigned short* __restrict__ dst, int n4) {
  int i = blockIdx.x * blockDim.x + threadIdx.x;
  if (i >= n4) return;
  float4 a = ((const float4*)src)[i];
  union { unsigned short s[4]; uint2 v; } o;
  o.s[0] = f2bf(a.x); o.s[1] = f2bf(a.y); o.s[2] = f2bf(a.z); o.s[3] = f2bf(a.w);
  ((uint2*)dst)[i] = o.v;
}

// ---------------- router: one wave per token, fp32 ----------------
__global__ void router_k(const float* __restrict__ x, const float* __restrict__ Wr,
                         int* __restrict__ cnt, int* __restrict__ tokE,
                         float2* __restrict__ tokW) {
  int gt = blockIdx.x * blockDim.x + threadIdx.x;
  int t = gt >> 6;
  int lane = threadIdx.x & 63;
  const float4* xr = (const float4*)(x + (size_t)t * DDIM);
  float4 xv[4];
#pragma unroll
  for (int j = 0; j < 4; ++j) xv[j] = xr[j * 64 + lane];   // coalesced
  float s[NEXP];
#pragma unroll
  for (int e = 0; e < NEXP; ++e) {
    const float4* wr = (const float4*)(Wr + e * DDIM);
    float acc = 0.f;
#pragma unroll
    for (int j = 0; j < 4; ++j) {
      float4 wv = wr[j * 64 + lane];
      acc += xv[j].x * wv.x + xv[j].y * wv.y + xv[j].z * wv.z + xv[j].w * wv.w;
    }
    s[e] = acc;
  }
#pragma unroll
  for (int e = 0; e < NEXP; ++e) {
    float v = s[e];
#pragma unroll
    for (int o = 32; o >= 1; o >>= 1) v += __shfl_xor(v, o, 64);
    s[e] = v;
  }
  if (lane == 0) {
    int e1 = 0; float m1 = s[0];
#pragma unroll
    for (int e = 1; e < NEXP; ++e) if (s[e] > m1) { m1 = s[e]; e1 = e; }
    int e2 = -1; float m2 = -3.4e38f;
#pragma unroll
    for (int e = 0; e < NEXP; ++e) {
      if (e == e1) continue;
      if (s[e] > m2) { m2 = s[e]; e2 = e; }
    }
    // renormalized top-2 softmax weights (full denominator cancels)
    float dd = expf(m2 - m1);
    float w1 = 1.f / (1.f + dd);
    float w2 = dd / (1.f + dd);
    tokE[t] = e1 | (e2 << 8);
    tokW[t] = make_float2(w1, w2);
    atomicAdd(&cnt[e1], 1);
    atomicAdd(&cnt[e2], 1);
  }
}

// ---------------- exclusive prefix over 8 counts ----------------
__global__ void offsets_k(const int* __restrict__ cnt, int* __restrict__ off,
                          int* __restrict__ cur) {
  if (threadIdx.x == 0) {
    int a = 0;
    for (int e = 0; e < NEXP; ++e) { off[e] = a; a += cnt[e]; cur[e] = 0; }
  }
}

// wave-aggregated bucket slot allocation (cuts same-address atomics 64x)
__device__ __forceinline__ int bucket_slot(int* cur, int e_sel) {
  int lane = threadIdx.x & 63;
  int slot = 0;
#pragma unroll
  for (int e = 0; e < NEXP; ++e) {
    unsigned long long m = __ballot(e_sel == e);
    if (e_sel == e) {
      unsigned long long below = m & ((1ull << lane) - 1ull);
      int leader = __ffsll((long long)m) - 1;
      int base = 0;
      if (lane == leader) base = atomicAdd(&cur[e], (int)__popcll(m));
      base = __shfl(base, leader, 64);
      slot = base + (int)__popcll(below);
    }
  }
  return slot;
}

__global__ void place_k(const int* __restrict__ tokE, const float2* __restrict__ tokW,
                        const int* __restrict__ off, int* __restrict__ cur,
                        int* __restrict__ asgT, float* __restrict__ asgW) {
  int t = blockIdx.x * blockDim.x + threadIdx.x;
  if (t >= NTOK) return;
  int pk = tokE[t];
  float2 w = tokW[t];
  int e1 = pk & 0xFF, e2 = (pk >> 8) & 0xFF;
  int p1 = off[e1] + bucket_slot(cur, e1);
  asgT[p1] = t; asgW[p1] = w.x;
  int p2 = off[e2] + bucket_slot(cur, e2);
  asgT[p2] = t; asgW[p2] = w.y;
}

// ---------------- GEMM1: h = gelu(gather(x) @ W1[e]^T + b1[e]) ----------------
// 128x128 tile, BK=32, 4 waves, 16x16x32 bf16 MFMA.
// LDS is fragment-major: group g (16 rows/cols) stored as [kchunk(4)][r(16)][8 bf16]
// so lane l's ds_read_b128 at g*1024 + l*16 is conflict-free AND matches the
// linear global_load_lds destination (per-lane SOURCE addresses do the permute).
__global__ __launch_bounds__(256)
void gemm1_k(const unsigned short* __restrict__ xb, const unsigned short* __restrict__ w1b,
             const float* __restrict__ b1, const int* __restrict__ cntp,
             const int* __restrict__ offp, const int* __restrict__ asgT,
             unsigned short* __restrict__ h) {
  const int e = blockIdx.z;
  const int cnt = cntp[e];
  const int m0 = blockIdx.x * 128;
  if (m0 >= cnt) return;
  const int off = offp[e];
  const int n0 = blockIdx.y * 128;

  __shared__ __align__(16) unsigned short As[2][4096];
  __shared__ __align__(16) unsigned short Bs[2][4096];

  const int tid = threadIdx.x;
  const int w = tid >> 6, lane = tid & 63;
  const int r = lane & 15, kc = lane >> 4;

  const unsigned short* srcA[2];
  const unsigned short* srcB[2];
#pragma unroll
  for (int j = 0; j < 2; ++j) {
    int g = j * 4 + w;
    int rowt = m0 + g * 16 + r;
    int rowc = (rowt < cnt) ? rowt : m0;            // clamp (m0 is valid)
    int tok = asgT[off + rowc];
    srcA[j] = xb + (size_t)tok * DDIM + kc * 8;
    int coln = n0 + g * 16 + r;
    srcB[j] = w1b + (size_t)e * DDIM * DDIM + (size_t)coln * DDIM + kc * 8;
  }

  f32x4 acc[4][4];
#pragma unroll
  for (int i = 0; i < 4; ++i)
#pragma unroll
    for (int j = 0; j < 4; ++j) acc[i][j] = (f32x4){0.f, 0.f, 0.f, 0.f};

  auto stage = [&](int buf, int k0) {
#pragma unroll
    for (int j = 0; j < 2; ++j) {
      int g = j * 4 + w;
      GL2LDS(srcA[j] + k0, &As[buf][g * 512 + lane * 8]);
      GL2LDS(srcB[j] + k0, &Bs[buf][g * 512 + lane * 8]);
    }
  };

  const int wr = w >> 1, wc = w & 1;
  stage(0, 0);
#pragma unroll 2
  for (int s = 0; s < 32; ++s) {
    int buf = s & 1;
    __syncthreads();                 // drains prior stage (vmcnt) + read fence
    if (s + 1 < 32) stage(buf ^ 1, (s + 1) * 32);
    bf16x8 af[4], bv[4];
#pragma unroll
    for (int i = 0; i < 4; ++i) {
      af[i] = *(const bf16x8*)&As[buf][(wr * 4 + i) * 512 + lane * 8];
      bv[i] = *(const bf16x8*)&Bs[buf][(wc * 4 + i) * 512 + lane * 8];
    }
#pragma unroll
    for (int i = 0; i < 4; ++i)
#pragma unroll
      for (int j = 0; j < 4; ++j)
        acc[i][j] = __builtin_amdgcn_mfma_f32_16x16x32_bf16(af[i], bv[j], acc[i][j], 0, 0, 0);
  }

  float bcol[4];
#pragma unroll
  for (int j = 0; j < 4; ++j) bcol[j] = b1[e * DDIM + n0 + wc * 64 + j * 16 + r];
#pragma unroll
  for (int i = 0; i < 4; ++i) {
#pragma unroll
    for (int q = 0; q < 4; ++q) {
      int grow = m0 + wr * 64 + i * 16 + kc * 4 + q;   // C/D: row=(l>>4)*4+q, col=l&15
      if (grow < cnt) {
        size_t hrow = (size_t)(off + grow) * DDIM;
#pragma unroll
        for (int j = 0; j < 4; ++j) {
          int col = n0 + wc * 64 + j * 16 + r;
          h[hrow + col] = f2bf(gelu_exact(acc[i][j][q] + bcol[j]));
        }
      }
    }
  }
}

// ---------------- GEMM2: out[tok] += w * (h @ W2[e]^T + b2[e]) ----------------
__global__ __launch_bounds__(256)
void gemm2_k(const unsigned short* __restrict__ hsrc, const unsigned short* __restrict__ w2b,
             const float* __restrict__ b2, const int* __restrict__ cntp,
             const int* __restrict__ offp, const int* __restrict__ asgT,
             const float* __restrict__ asgW, float* __restrict__ out) {
  const int e = blockIdx.z;
  const int cnt = cntp[e];
  const int m0 = blockIdx.x * 128;
  if (m0 >= cnt) return;
  const int off = offp[e];
  const int n0 = blockIdx.y * 128;

  __shared__ __align__(16) unsigned short As[2][4096];
  __shared__ __align__(16) unsigned short Bs[2][4096];

  const int tid = threadIdx.x;
  const int w = tid >> 6, lane = tid & 63;
  const int r = lane & 15, kc = lane >> 4;

  const unsigned short* srcA[2];
  const unsigned short* srcB[2];
#pragma unroll
  for (int j = 0; j < 2; ++j) {
    int g = j * 4 + w;
    int rowt = m0 + g * 16 + r;
    int rowc = (rowt < cnt) ? rowt : m0;
    srcA[j] = hsrc + (size_t)(off + rowc) * DDIM + kc * 8;
    int coln = n0 + g * 16 + r;
    srcB[j] = w2b + (size_t)e * DDIM * DDIM + (size_t)coln * DDIM + kc * 8;
  }

  f32x4 acc[4][4];
#pragma unroll
  for (int i = 0; i < 4; ++i)
#pragma unroll
    for (int j = 0; j < 4; ++j) acc[i][j] = (f32x4){0.f, 0.f, 0.f, 0.f};

  auto stage = [&](int buf, int k0) {
#pragma unroll
    for (int j = 0; j < 2; ++j) {
      int g = j * 4 + w;
      GL2LDS(srcA[j] + k0, &As[buf][g * 512 + lane * 8]);
      GL2LDS(srcB[j] + k0, &Bs[buf][g * 512 + lane * 8]);
    }
  };

  const int wr = w >> 1, wc = w & 1;
  stage(0, 0);
#pragma unroll 2
  for (int s = 0; s < 32; ++s) {
    int buf = s & 1;
    __syncthreads();
    if (s + 1 < 32) stage(buf ^ 1, (s + 1) * 32);
    bf16x8 af[4], bv[4];
#pragma unroll
    for (int i = 0; i < 4; ++i) {
      af[i] = *(const bf16x8*)&As[buf][(wr * 4 + i) * 512 + lane * 8];
      bv[i] = *(const bf16x8*)&Bs[buf][(wc * 4 + i) * 512 + lane * 8];
    }
#pragma unroll
    for (int i = 0; i < 4; ++i)
#pragma unroll
      for (int j = 0; j < 4; ++j)
        acc[i][j] = __builtin_amdgcn_mfma_f32_16x16x32_bf16(af[i], bv[j], acc[i][j], 0, 0, 0);
  }

  float bcol[4];
#pragma unroll
  for (int j = 0; j < 4; ++j) bcol[j] = b2[e * DDIM + n0 + wc * 64 + j * 16 + r];
#pragma unroll
  for (int i = 0; i < 4; ++i) {
#pragma unroll
    for (int q = 0; q < 4; ++q) {
      int grow = m0 + wr * 64 + i * 16 + kc * 4 + q;
      if (grow < cnt) {
        int tok = asgT[off + grow];
        float wgt = asgW[off + grow];
        float* orow = out + (size_t)tok * DDIM;
#pragma unroll
        for (int j = 0; j < 4; ++j) {
          int col = n0 + wc * 64 + j * 16 + r;
          atomicAdd(&orow[col], wgt * (acc[i][j][q] + bcol[j]));
        }
      }
    }
  }
}

// ---------------- launch ----------------
// ws layout (bytes):
//   0      cnt[8] | 64 off[8] | 128 cur[8]
//   256    tokE[NTOK] int32            (64 KB)
//   +64K   tokW[NTOK] float2           (128 KB)
//   ...    asgT[2*NTOK] int32, asgW[2*NTOK] float (128 KB each)
//   1 MB   xb  bf16 [NTOK][D]          (32 MB)
//   33 MB  w1b bf16 [E][D][D]          (16 MB)
//   49 MB  w2b bf16 [E][D][D]          (16 MB)
//   65 MB  h   bf16 [2*NTOK][D]        (64 MB)   -> total 129 MB
extern "C" void kernel_launch(void* const* d_in, const int* in_sizes, int n_in,
                              void* d_out, int out_size, void* d_ws, size_t ws_size,
                              hipStream_t stream) {
  (void)in_sizes; (void)n_in; (void)ws_size;
  const float* x  = (const float*)d_in[0];
  const float* Wr = (const float*)d_in[1];
  const float* W1 = (const float*)d_in[2];
  const float* b1 = (const float*)d_in[3];
  const float* W2 = (const float*)d_in[4];
  const float* b2 = (const float*)d_in[5];
  float* out = (float*)d_out;

  char* ws = (char*)d_ws;
  int*    cnt  = (int*)(ws + 0);
  int*    off  = (int*)(ws + 64);
  int*    cur  = (int*)(ws + 128);
  int*    tokE = (int*)(ws + 256);
  float2* tokW = (float2*)(ws + 256 + 65536);
  int*    asgT = (int*)(ws + 256 + 65536 + 131072);
  float*  asgW = (float*)(ws + 256 + 65536 + 131072 + 131072);
  unsigned short* xb  = (unsigned short*)(ws + (size_t)(1u << 20));
  unsigned short* w1b = (unsigned short*)(ws + (size_t)33 * (1u << 20));
  unsigned short* w2b = (unsigned short*)(ws + (size_t)49 * (1u << 20));
  unsigned short* h   = (unsigned short*)(ws + (size_t)65 * (1u << 20));

  hipMemsetAsync(ws, 0, 256, stream);
  hipMemsetAsync(d_out, 0, (size_t)out_size * sizeof(float), stream);

  const int nX = NTOK * DDIM;          // 16,777,216
  const int nW = NEXP * DDIM * DDIM;   //  8,388,608
  cast_k<<<(nX / 4) / 256, 256, 0, stream>>>(x,  xb,  nX / 4);
  cast_k<<<(nW / 4) / 256, 256, 0, stream>>>(W1, w1b, nW / 4);
  cast_k<<<(nW / 4) / 256, 256, 0, stream>>>(W2, w2b, nW / 4);

  router_k<<<NTOK / 4, 256, 0, stream>>>(x, Wr, cnt, tokE, tokW);
  offsets_k<<<1, 64, 0, stream>>>(cnt, off, cur);
  place_k<<<NTOK / 256, 256, 0, stream>>>(tokE, tokW, off, cur, asgT, asgW);

  dim3 ggrid(128, 8, NEXP);   // worst-case tiles_m; blocks past cnt[e] exit
  gemm1_k<<<ggrid, 256, 0, stream>>>(xb, w1b, b1, cnt, off, asgT, h);
  gemm2_k<<<ggrid, 256, 0, stream>>>(h, w2b, b2, cnt, off, asgT, asgW, out);
}

// Round 4
// 742.020 us; speedup vs baseline: 1.5380x; 1.5380x over previous
//
#include <hip/hip_runtime.h>
#include <hip/hip_bf16.h>
#include <cstdint>
#include <cstddef>

#define NTOK 16384   // B*L = 4*4096
#define DDIM 1024
#define NEXP 8
#define CPAD 32      // counter padding: 32 ints = 128B per counter

typedef __attribute__((ext_vector_type(8))) short bf16x8;
typedef __attribute__((ext_vector_type(4))) float f32x4;

__device__ __forceinline__ unsigned short f2bf(float f) {
  union { float f; unsigned u; } c; c.f = f;
  unsigned r = (c.u + 0x7FFFu + ((c.u >> 16) & 1u)) >> 16;  // RNE
  return (unsigned short)r;
}

__device__ __forceinline__ float gelu_exact(float v) {
  return 0.5f * v * (1.0f + erff(v * 0.70710678118654752440f));
}

// direct global->LDS async copy, 16B per lane. LDS dest must be linear
// (wave-uniform base + lane*16); source address is per-lane.
#define GL2LDS(gp, lp) __builtin_amdgcn_global_load_lds( \
    (__attribute__((address_space(1))) void*)(gp),       \
    (__attribute__((address_space(3))) void*)(lp), 16, 0, 0)

// ---------------- cast fp32 -> bf16, 4 elems/thread (weights) ----------------
__global__ void cast_k(const float* __restrict__ src, unsigned short* __restrict__ dst, int n4) {
  int i = blockIdx.x * blockDim.x + threadIdx.x;
  if (i >= n4) return;
  float4 a = ((const float4*)src)[i];
  union { unsigned short s[4]; uint2 v; } o;
  o.s[0] = f2bf(a.x); o.s[1] = f2bf(a.y); o.s[2] = f2bf(a.z); o.s[3] = f2bf(a.w);
  ((uint2*)dst)[i] = o.v;
}

// ---------------- fused x-cast + router: one block per token, NO atomics ----------------
__global__ __launch_bounds__(256)
void castx_router_k(const float* __restrict__ x, const float* __restrict__ Wr,
                    unsigned short* __restrict__ xb, int* __restrict__ tokE,
                    float2* __restrict__ tokW) {
  const int t = blockIdx.x;
  const int tid = threadIdx.x;
  const int w = tid >> 6, lane = tid & 63;

  float4 xv = ((const float4*)x)[(size_t)t * 256 + tid];   // coalesced 16B/thread
  union { unsigned short s[4]; uint2 v; } o;
  o.s[0] = f2bf(xv.x); o.s[1] = f2bf(xv.y); o.s[2] = f2bf(xv.z); o.s[3] = f2bf(xv.w);
  ((uint2*)xb)[(size_t)t * 256 + tid] = o.v;

  const float4* Wr4 = (const float4*)Wr;                   // 32KB, L1-resident
  float p[NEXP];
#pragma unroll
  for (int e = 0; e < NEXP; ++e) {
    float4 wv = Wr4[e * 256 + tid];
    p[e] = xv.x * wv.x + xv.y * wv.y + xv.z * wv.z + xv.w * wv.w;
  }
  // wave reduce: 8 independent 6-step chains (ILP hides DS latency)
#pragma unroll
  for (int e = 0; e < NEXP; ++e) {
    float v = p[e];
#pragma unroll
    for (int off = 32; off >= 1; off >>= 1) v += __shfl_xor(v, off, 64);
    p[e] = v;
  }
  __shared__ float red[4][NEXP];
  if (lane == 0) {
#pragma unroll
    for (int e = 0; e < NEXP; ++e) red[w][e] = p[e];
  }
  __syncthreads();
  if (tid == 0) {
    float s[NEXP];
#pragma unroll
    for (int e = 0; e < NEXP; ++e) s[e] = red[0][e] + red[1][e] + red[2][e] + red[3][e];
    int e1 = 0; float m1 = s[0];
#pragma unroll
    for (int e = 1; e < NEXP; ++e) if (s[e] > m1) { m1 = s[e]; e1 = e; }
    int e2 = -1; float m2 = -3.4e38f;
#pragma unroll
    for (int e = 0; e < NEXP; ++e) {
      if (e == e1) continue;
      if (s[e] > m2) { m2 = s[e]; e2 = e; }
    }
    float dd = expf(m2 - m1);                 // renormalized top-2 softmax
    tokE[t] = e1 | (e2 << 8);
    tokW[t] = make_float2(1.f / (1.f + dd), dd / (1.f + dd));
  }
}

// ---------------- histogram: ballot-aggregated, 8 atomics/block on padded lines ----------------
__global__ __launch_bounds__(256)
void hist_k(const int* __restrict__ tokE, int* __restrict__ cnt) {
  const int t = blockIdx.x * blockDim.x + threadIdx.x;
  const int w = threadIdx.x >> 6, lane = threadIdx.x & 63;
  const int pk = tokE[t];
  const int e1 = pk & 0xFF, e2 = (pk >> 8) & 0xFF;
  __shared__ int h[4][NEXP];
#pragma unroll
  for (int e = 0; e < NEXP; ++e) {
    int c = (int)__popcll(__ballot(e1 == e)) + (int)__popcll(__ballot(e2 == e));
    if (lane == 0) h[w][e] = c;
  }
  __syncthreads();
  if (threadIdx.x < NEXP) {
    int tot = h[0][threadIdx.x] + h[1][threadIdx.x] + h[2][threadIdx.x] + h[3][threadIdx.x];
    atomicAdd(&cnt[threadIdx.x * CPAD], tot);
  }
}

// ---------------- exclusive prefix over 8 padded counts ----------------
__global__ void offsets_k(const int* __restrict__ cnt, int* __restrict__ off) {
  if (threadIdx.x == 0) {
    int a = 0;
    for (int e = 0; e < NEXP; ++e) { off[e] = a; a += cnt[e * CPAD]; }
  }
}

// wave-aggregated bucket slot allocation on PADDED counters
__device__ __forceinline__ int bucket_slot(int* cur, int e_sel) {
  int lane = threadIdx.x & 63;
  int slot = 0;
#pragma unroll
  for (int e = 0; e < NEXP; ++e) {
    unsigned long long m = __ballot(e_sel == e);
    if (e_sel == e) {
      unsigned long long below = m & ((1ull << lane) - 1ull);
      int leader = __ffsll((long long)m) - 1;
      int base = 0;
      if (lane == leader) base = atomicAdd(&cur[e * CPAD], (int)__popcll(m));
      base = __shfl(base, leader, 64);
      slot = base + (int)__popcll(below);
    }
  }
  return slot;
}

__global__ __launch_bounds__(256)
void place_k(const int* __restrict__ tokE, const float2* __restrict__ tokW,
             const int* __restrict__ off, int* __restrict__ cur,
             int* __restrict__ asgT, float* __restrict__ asgW) {
  int t = blockIdx.x * blockDim.x + threadIdx.x;
  if (t >= NTOK) return;
  int pk = tokE[t];
  float2 w = tokW[t];
  int e1 = pk & 0xFF, e2 = (pk >> 8) & 0xFF;
  int p1 = off[e1] + bucket_slot(cur, e1);
  asgT[p1] = t; asgW[p1] = w.x;
  int p2 = off[e2] + bucket_slot(cur, e2);
  asgT[p2] = t; asgW[p2] = w.y;
}

// ---------------- GEMM1: h = gelu(gather(x) @ W1[e]^T + b1[e]) ----------------
// 128x128 tile, BK=32, 4 waves, 16x16x32 bf16 MFMA. Fragment-major LDS:
// conflict-free ds_read_b128 matching linear global_load_lds dest.
__global__ __launch_bounds__(256)
void gemm1_k(const unsigned short* __restrict__ xb, const unsigned short* __restrict__ w1b,
             const float* __restrict__ b1, const int* __restrict__ cntp,
             const int* __restrict__ offp, const int* __restrict__ asgT,
             unsigned short* __restrict__ h) {
  const int e = blockIdx.z;
  const int cnt = cntp[e * CPAD];
  const int m0 = blockIdx.x * 128;
  if (m0 >= cnt) return;
  const int off = offp[e];
  const int n0 = blockIdx.y * 128;

  __shared__ __align__(16) unsigned short As[2][4096];
  __shared__ __align__(16) unsigned short Bs[2][4096];

  const int tid = threadIdx.x;
  const int w = tid >> 6, lane = tid & 63;
  const int r = lane & 15, kc = lane >> 4;

  const unsigned short* srcA[2];
  const unsigned short* srcB[2];
#pragma unroll
  for (int j = 0; j < 2; ++j) {
    int g = j * 4 + w;
    int rowt = m0 + g * 16 + r;
    int rowc = (rowt < cnt) ? rowt : m0;            // clamp (m0 is valid)
    int tok = asgT[off + rowc];
    srcA[j] = xb + (size_t)tok * DDIM + kc * 8;
    int coln = n0 + g * 16 + r;
    srcB[j] = w1b + (size_t)e * DDIM * DDIM + (size_t)coln * DDIM + kc * 8;
  }

  f32x4 acc[4][4];
#pragma unroll
  for (int i = 0; i < 4; ++i)
#pragma unroll
    for (int j = 0; j < 4; ++j) acc[i][j] = (f32x4){0.f, 0.f, 0.f, 0.f};

  auto stage = [&](int buf, int k0) {
#pragma unroll
    for (int j = 0; j < 2; ++j) {
      int g = j * 4 + w;
      GL2LDS(srcA[j] + k0, &As[buf][g * 512 + lane * 8]);
      GL2LDS(srcB[j] + k0, &Bs[buf][g * 512 + lane * 8]);
    }
  };

  const int wr = w >> 1, wc = w & 1;
  stage(0, 0);
#pragma unroll 2
  for (int s = 0; s < 32; ++s) {
    int buf = s & 1;
    __syncthreads();
    if (s + 1 < 32) stage(buf ^ 1, (s + 1) * 32);
    bf16x8 af[4], bv[4];
#pragma unroll
    for (int i = 0; i < 4; ++i) {
      af[i] = *(const bf16x8*)&As[buf][(wr * 4 + i) * 512 + lane * 8];
      bv[i] = *(const bf16x8*)&Bs[buf][(wc * 4 + i) * 512 + lane * 8];
    }
#pragma unroll
    for (int i = 0; i < 4; ++i)
#pragma unroll
      for (int j = 0; j < 4; ++j)
        acc[i][j] = __builtin_amdgcn_mfma_f32_16x16x32_bf16(af[i], bv[j], acc[i][j], 0, 0, 0);
  }

  float bcol[4];
#pragma unroll
  for (int j = 0; j < 4; ++j) bcol[j] = b1[e * DDIM + n0 + wc * 64 + j * 16 + r];
#pragma unroll
  for (int i = 0; i < 4; ++i) {
#pragma unroll
    for (int q = 0; q < 4; ++q) {
      int grow = m0 + wr * 64 + i * 16 + kc * 4 + q;   // C/D: row=(l>>4)*4+q, col=l&15
      if (grow < cnt) {
        size_t hrow = (size_t)(off + grow) * DDIM;
#pragma unroll
        for (int j = 0; j < 4; ++j) {
          int col = n0 + wc * 64 + j * 16 + r;
          h[hrow + col] = f2bf(gelu_exact(acc[i][j][q] + bcol[j]));
        }
      }
    }
  }
}

// ---------------- GEMM2: out[tok] += w * (h @ W2[e]^T + b2[e]) ----------------
__global__ __launch_bounds__(256)
void gemm2_k(const unsigned short* __restrict__ hsrc, const unsigned short* __restrict__ w2b,
             const float* __restrict__ b2, const int* __restrict__ cntp,
             const int* __restrict__ offp, const int* __restrict__ asgT,
             const float* __restrict__ asgW, float* __restrict__ out) {
  const int e = blockIdx.z;
  const int cnt = cntp[e * CPAD];
  const int m0 = blockIdx.x * 128;
  if (m0 >= cnt) return;
  const int off = offp[e];
  const int n0 = blockIdx.y * 128;

  __shared__ __align__(16) unsigned short As[2][4096];
  __shared__ __align__(16) unsigned short Bs[2][4096];

  const int tid = threadIdx.x;
  const int w = tid >> 6, lane = tid & 63;
  const int r = lane & 15, kc = lane >> 4;

  const unsigned short* srcA[2];
  const unsigned short* srcB[2];
#pragma unroll
  for (int j = 0; j < 2; ++j) {
    int g = j * 4 + w;
    int rowt = m0 + g * 16 + r;
    int rowc = (rowt < cnt) ? rowt : m0;
    srcA[j] = hsrc + (size_t)(off + rowc) * DDIM + kc * 8;
    int coln = n0 + g * 16 + r;
    srcB[j] = w2b + (size_t)e * DDIM * DDIM + (size_t)coln * DDIM + kc * 8;
  }

  f32x4 acc[4][4];
#pragma unroll
  for (int i = 0; i < 4; ++i)
#pragma unroll
    for (int j = 0; j < 4; ++j) acc[i][j] = (f32x4){0.f, 0.f, 0.f, 0.f};

  auto stage = [&](int buf, int k0) {
#pragma unroll
    for (int j = 0; j < 2; ++j) {
      int g = j * 4 + w;
      GL2LDS(srcA[j] + k0, &As[buf][g * 512 + lane * 8]);
      GL2LDS(srcB[j] + k0, &Bs[buf][g * 512 + lane * 8]);
    }
  };

  const int wr = w >> 1, wc = w & 1;
  stage(0, 0);
#pragma unroll 2
  for (int s = 0; s < 32; ++s) {
    int buf = s & 1;
    __syncthreads();
    if (s + 1 < 32) stage(buf ^ 1, (s + 1) * 32);
    bf16x8 af[4], bv[4];
#pragma unroll
    for (int i = 0; i < 4; ++i) {
      af[i] = *(const bf16x8*)&As[buf][(wr * 4 + i) * 512 + lane * 8];
      bv[i] = *(const bf16x8*)&Bs[buf][(wc * 4 + i) * 512 + lane * 8];
    }
#pragma unroll
    for (int i = 0; i < 4; ++i)
#pragma unroll
      for (int j = 0; j < 4; ++j)
        acc[i][j] = __builtin_amdgcn_mfma_f32_16x16x32_bf16(af[i], bv[j], acc[i][j], 0, 0, 0);
  }

  float bcol[4];
#pragma unroll
  for (int j = 0; j < 4; ++j) bcol[j] = b2[e * DDIM + n0 + wc * 64 + j * 16 + r];
#pragma unroll
  for (int i = 0; i < 4; ++i) {
#pragma unroll
    for (int q = 0; q < 4; ++q) {
      int grow = m0 + wr * 64 + i * 16 + kc * 4 + q;
      if (grow < cnt) {
        int tok = asgT[off + grow];
        float wgt = asgW[off + grow];
        float* orow = out + (size_t)tok * DDIM;
#pragma unroll
        for (int j = 0; j < 4; ++j) {
          int col = n0 + wc * 64 + j * 16 + r;
          atomicAdd(&orow[col], wgt * (acc[i][j][q] + bcol[j]));
        }
      }
    }
  }
}

// ---------------- launch ----------------
// ws layout (bytes):
//   0      cnt[8] padded x128B (1KB)
//   4096   off[8]
//   8192   cur[8] padded x128B (1KB)
//   16384  tokE[NTOK] int32 (64KB) | +64K tokW float2 (128KB)
//   ...    asgT[2N] (128KB) | asgW[2N] (128KB)
//   1 MB   xb bf16 (32MB) | 33MB w1b (16MB) | 49MB w2b (16MB) | 65MB h (64MB)
extern "C" void kernel_launch(void* const* d_in, const int* in_sizes, int n_in,
                              void* d_out, int out_size, void* d_ws, size_t ws_size,
                              hipStream_t stream) {
  (void)in_sizes; (void)n_in; (void)ws_size;
  const float* x  = (const float*)d_in[0];
  const float* Wr = (const float*)d_in[1];
  const float* W1 = (const float*)d_in[2];
  const float* b1 = (const float*)d_in[3];
  const float* W2 = (const float*)d_in[4];
  const float* b2 = (const float*)d_in[5];
  float* out = (float*)d_out;

  char* ws = (char*)d_ws;
  int*    cnt  = (int*)(ws + 0);
  int*    off  = (int*)(ws + 4096);
  int*    cur  = (int*)(ws + 8192);
  int*    tokE = (int*)(ws + 16384);
  float2* tokW = (float2*)(ws + 16384 + 65536);
  int*    asgT = (int*)(ws + 16384 + 65536 + 131072);
  float*  asgW = (float*)(ws + 16384 + 65536 + 131072 + 131072);
  unsigned short* xb  = (unsigned short*)(ws + (size_t)(1u << 20));
  unsigned short* w1b = (unsigned short*)(ws + (size_t)33 * (1u << 20));
  unsigned short* w2b = (unsigned short*)(ws + (size_t)49 * (1u << 20));
  unsigned short* h   = (unsigned short*)(ws + (size_t)65 * (1u << 20));

  hipMemsetAsync(ws, 0, 16384, stream);                       // cnt + cur
  hipMemsetAsync(d_out, 0, (size_t)out_size * sizeof(float), stream);

  const int nW = NEXP * DDIM * DDIM;   // 8,388,608
  cast_k<<<(nW / 4) / 256, 256, 0, stream>>>(W1, w1b, nW / 4);
  cast_k<<<(nW / 4) / 256, 256, 0, stream>>>(W2, w2b, nW / 4);

  castx_router_k<<<NTOK, 256, 0, stream>>>(x, Wr, xb, tokE, tokW);
  hist_k<<<NTOK / 256, 256, 0, stream>>>(tokE, cnt);
  offsets_k<<<1, 64, 0, stream>>>(cnt, off);
  place_k<<<NTOK / 256, 256, 0, stream>>>(tokE, tokW, off, cur, asgT, asgW);

  dim3 ggrid(128, 8, NEXP);   // worst-case tiles_m; blocks past cnt[e] exit
  gemm1_k<<<ggrid, 256, 0, stream>>>(xb, w1b, b1, cnt, off, asgT, h);
  gemm2_k<<<ggrid, 256, 0, stream>>>(h, w2b, b2, cnt, off, asgT, asgW, out);
}

// Round 5
// 715.426 us; speedup vs baseline: 1.5951x; 1.0372x over previous
//
#include <hip/hip_runtime.h>
#include <hip/hip_bf16.h>
#include <cstdint>
#include <cstddef>

#define NTOK 16384   // B*L = 4*4096
#define DDIM 1024
#define NEXP 8
#define CPAD 32      // counter padding: 32 ints = 128B per counter

typedef __attribute__((ext_vector_type(8))) short bf16x8;
typedef __attribute__((ext_vector_type(4))) float f32x4;

__device__ __forceinline__ unsigned short f2bf(float f) {
  union { float f; unsigned u; } c; c.f = f;
  unsigned r = (c.u + 0x7FFFu + ((c.u >> 16) & 1u)) >> 16;  // RNE
  return (unsigned short)r;
}

__device__ __forceinline__ float gelu_exact(float v) {
  return 0.5f * v * (1.0f + erff(v * 0.70710678118654752440f));
}

// direct global->LDS async copy, 16B per lane. LDS dest must be linear
// (wave-uniform base + lane*16); source address is per-lane.
#define GL2LDS(gp, lp) __builtin_amdgcn_global_load_lds( \
    (__attribute__((address_space(1))) void*)(gp),       \
    (__attribute__((address_space(3))) void*)(lp), 16, 0, 0)

// ---------------- cast fp32 -> bf16, 4 elems/thread (weights) ----------------
__global__ void cast_k(const float* __restrict__ src, unsigned short* __restrict__ dst, int n4) {
  int i = blockIdx.x * blockDim.x + threadIdx.x;
  if (i >= n4) return;
  float4 a = ((const float4*)src)[i];
  union { unsigned short s[4]; uint2 v; } o;
  o.s[0] = f2bf(a.x); o.s[1] = f2bf(a.y); o.s[2] = f2bf(a.z); o.s[3] = f2bf(a.w);
  ((uint2*)dst)[i] = o.v;
}

// ---------------- fused x-cast + router: one block per token, NO atomics ----------------
__global__ __launch_bounds__(256)
void castx_router_k(const float* __restrict__ x, const float* __restrict__ Wr,
                    unsigned short* __restrict__ xb, int* __restrict__ tokE,
                    float2* __restrict__ tokW) {
  const int t = blockIdx.x;
  const int tid = threadIdx.x;
  const int w = tid >> 6, lane = tid & 63;

  float4 xv = ((const float4*)x)[(size_t)t * 256 + tid];   // coalesced 16B/thread
  union { unsigned short s[4]; uint2 v; } o;
  o.s[0] = f2bf(xv.x); o.s[1] = f2bf(xv.y); o.s[2] = f2bf(xv.z); o.s[3] = f2bf(xv.w);
  ((uint2*)xb)[(size_t)t * 256 + tid] = o.v;

  const float4* Wr4 = (const float4*)Wr;                   // 32KB, L1-resident
  float p[NEXP];
#pragma unroll
  for (int e = 0; e < NEXP; ++e) {
    float4 wv = Wr4[e * 256 + tid];
    p[e] = xv.x * wv.x + xv.y * wv.y + xv.z * wv.z + xv.w * wv.w;
  }
#pragma unroll
  for (int e = 0; e < NEXP; ++e) {
    float v = p[e];
#pragma unroll
    for (int off = 32; off >= 1; off >>= 1) v += __shfl_xor(v, off, 64);
    p[e] = v;
  }
  __shared__ float red[4][NEXP];
  if (lane == 0) {
#pragma unroll
    for (int e = 0; e < NEXP; ++e) red[w][e] = p[e];
  }
  __syncthreads();
  if (tid == 0) {
    float s[NEXP];
#pragma unroll
    for (int e = 0; e < NEXP; ++e) s[e] = red[0][e] + red[1][e] + red[2][e] + red[3][e];
    int e1 = 0; float m1 = s[0];
#pragma unroll
    for (int e = 1; e < NEXP; ++e) if (s[e] > m1) { m1 = s[e]; e1 = e; }
    int e2 = -1; float m2 = -3.4e38f;
#pragma unroll
    for (int e = 0; e < NEXP; ++e) {
      if (e == e1) continue;
      if (s[e] > m2) { m2 = s[e]; e2 = e; }
    }
    float dd = expf(m2 - m1);                 // renormalized top-2 softmax
    tokE[t] = e1 | (e2 << 8);
    tokW[t] = make_float2(1.f / (1.f + dd), dd / (1.f + dd));
  }
}

// ---------------- histogram: ballot-aggregated, 8 atomics/block on padded lines ----------------
__global__ __launch_bounds__(256)
void hist_k(const int* __restrict__ tokE, int* __restrict__ cnt) {
  const int t = blockIdx.x * blockDim.x + threadIdx.x;
  const int w = threadIdx.x >> 6, lane = threadIdx.x & 63;
  const int pk = tokE[t];
  const int e1 = pk & 0xFF, e2 = (pk >> 8) & 0xFF;
  __shared__ int h[4][NEXP];
#pragma unroll
  for (int e = 0; e < NEXP; ++e) {
    int c = (int)__popcll(__ballot(e1 == e)) + (int)__popcll(__ballot(e2 == e));
    if (lane == 0) h[w][e] = c;
  }
  __syncthreads();
  if (threadIdx.x < NEXP) {
    int tot = h[0][threadIdx.x] + h[1][threadIdx.x] + h[2][threadIdx.x] + h[3][threadIdx.x];
    atomicAdd(&cnt[threadIdx.x * CPAD], tot);
  }
}

// ---------------- exclusive prefix over 8 padded counts ----------------
__global__ void offsets_k(const int* __restrict__ cnt, int* __restrict__ off) {
  if (threadIdx.x == 0) {
    int a = 0;
    for (int e = 0; e < NEXP; ++e) { off[e] = a; a += cnt[e * CPAD]; }
  }
}

// wave-aggregated bucket slot allocation on PADDED counters
__device__ __forceinline__ int bucket_slot(int* cur, int e_sel) {
  int lane = threadIdx.x & 63;
  int slot = 0;
#pragma unroll
  for (int e = 0; e < NEXP; ++e) {
    unsigned long long m = __ballot(e_sel == e);
    if (e_sel == e) {
      unsigned long long below = m & ((1ull << lane) - 1ull);
      int leader = __ffsll((long long)m) - 1;
      int base = 0;
      if (lane == leader) base = atomicAdd(&cur[e * CPAD], (int)__popcll(m));
      base = __shfl(base, leader, 64);
      slot = base + (int)__popcll(below);
    }
  }
  return slot;
}

__global__ __launch_bounds__(256)
void place_k(const int* __restrict__ tokE, const float2* __restrict__ tokW,
             const int* __restrict__ off, int* __restrict__ cur,
             int* __restrict__ asgT, float* __restrict__ asgW) {
  int t = blockIdx.x * blockDim.x + threadIdx.x;
  if (t >= NTOK) return;
  int pk = tokE[t];
  float2 w = tokW[t];
  int e1 = pk & 0xFF, e2 = (pk >> 8) & 0xFF;
  int p1 = off[e1] + bucket_slot(cur, e1);
  asgT[p1] = t; asgW[p1] = w.x;
  int p2 = off[e2] + bucket_slot(cur, e2);
  asgT[p2] = t; asgW[p2] = w.y;
}

// ================= 256x256 tile, BK=64, 8 waves (2M x 4N), 16x16x32 MFMA =================
// LDS fragment-major: 16 groups of 16 rows(cols); group = [ks(2)][kc(4)][r(16)][8 bf16]
// = 1024 shorts. One wave-issue of global_load_lds (64 lanes x 16B) fills exactly one
// (g, ks) 1024B sub-block -> linear dest, per-lane source does the permute.
// ds_read_b128 at g*1024 + ks*512 + lane*8 = 64 consecutive 16B slots -> 0 bank conflicts
// (verified: SQ_LDS_BANK_CONFLICT = 0 on the 128^2 version of this layout).

// ---------------- GEMM1: h = gelu(gather(x) @ W1[e]^T + b1[e]) ----------------
__global__ __launch_bounds__(512, 2)
void gemm1_k(const unsigned short* __restrict__ xb, const unsigned short* __restrict__ w1b,
             const float* __restrict__ b1, const int* __restrict__ cntp,
             const int* __restrict__ offp, const int* __restrict__ asgT,
             unsigned short* __restrict__ h) {
  const int e = blockIdx.z;
  const int cnt = cntp[e * CPAD];
  const int m0 = blockIdx.x * 256;
  if (m0 >= cnt) return;
  const int off = offp[e];
  const int n0 = blockIdx.y * 256;

  __shared__ __align__(16) unsigned short As[2][16384];  // 32KB per buffer
  __shared__ __align__(16) unsigned short Bs[2][16384];

  const int tid = threadIdx.x;
  const int w = tid >> 6, lane = tid & 63;
  const int r = lane & 15, kc = lane >> 4;
  const int wr = w >> 2, wc = w & 3;           // wave grid 2M x 4N

  // staging sources: wave w owns row-groups {2w, 2w+1} of A and col-groups {2w, 2w+1} of B
  const unsigned short* srcA[2];
  const unsigned short* srcB[2];
#pragma unroll
  for (int i = 0; i < 2; ++i) {
    int g = 2 * w + i;
    int rowt = m0 + g * 16 + r;
    int rowc = (rowt < cnt) ? rowt : m0;          // clamp to a valid row
    int tok = asgT[off + rowc];
    srcA[i] = xb + (size_t)tok * DDIM + kc * 8;
    int coln = n0 + g * 16 + r;
    srcB[i] = w1b + (size_t)e * DDIM * DDIM + (size_t)coln * DDIM + kc * 8;
  }

  f32x4 acc[8][4];
#pragma unroll
  for (int i = 0; i < 8; ++i)
#pragma unroll
    for (int j = 0; j < 4; ++j) acc[i][j] = (f32x4){0.f, 0.f, 0.f, 0.f};

  auto stage = [&](int buf, int k0) {
#pragma unroll
    for (int i = 0; i < 2; ++i) {
      int g = 2 * w + i;
#pragma unroll
      for (int ks = 0; ks < 2; ++ks) {
        GL2LDS(srcA[i] + k0 + ks * 32, &As[buf][g * 1024 + ks * 512 + lane * 8]);
        GL2LDS(srcB[i] + k0 + ks * 32, &Bs[buf][g * 1024 + ks * 512 + lane * 8]);
      }
    }
  };

  stage(0, 0);
  for (int s = 0; s < 16; ++s) {               // K = 1024 = 16 x 64
    int buf = s & 1;
    __syncthreads();                           // drains prior stage (vmcnt) + read fence
    if (s + 1 < 16) stage(buf ^ 1, (s + 1) * 64);
#pragma unroll
    for (int ks = 0; ks < 2; ++ks) {
      bf16x8 af[8], bv[4];
#pragma unroll
      for (int i = 0; i < 8; ++i)
        af[i] = *(const bf16x8*)&As[buf][(wr * 8 + i) * 1024 + ks * 512 + lane * 8];
#pragma unroll
      for (int j = 0; j < 4; ++j)
        bv[j] = *(const bf16x8*)&Bs[buf][(wc * 4 + j) * 1024 + ks * 512 + lane * 8];
#pragma unroll
      for (int i = 0; i < 8; ++i)
#pragma unroll
        for (int j = 0; j < 4; ++j)
          acc[i][j] = __builtin_amdgcn_mfma_f32_16x16x32_bf16(af[i], bv[j], acc[i][j], 0, 0, 0);
    }
  }

  float bcol[4];
#pragma unroll
  for (int j = 0; j < 4; ++j) bcol[j] = b1[e * DDIM + n0 + wc * 64 + j * 16 + r];
#pragma unroll
  for (int i = 0; i < 8; ++i) {
#pragma unroll
    for (int q = 0; q < 4; ++q) {
      int grow = m0 + wr * 128 + i * 16 + kc * 4 + q;   // C/D: row=(l>>4)*4+q, col=l&15
      if (grow < cnt) {
        size_t hrow = (size_t)(off + grow) * DDIM;
#pragma unroll
        for (int j = 0; j < 4; ++j) {
          int col = n0 + wc * 64 + j * 16 + r;
          h[hrow + col] = f2bf(gelu_exact(acc[i][j][q] + bcol[j]));
        }
      }
    }
  }
}

// ---------------- GEMM2: out[tok] += w * (h @ W2[e]^T + b2[e]) ----------------
__global__ __launch_bounds__(512, 2)
void gemm2_k(const unsigned short* __restrict__ hsrc, const unsigned short* __restrict__ w2b,
             const float* __restrict__ b2, const int* __restrict__ cntp,
             const int* __restrict__ offp, const int* __restrict__ asgT,
             const float* __restrict__ asgW, float* __restrict__ out) {
  const int e = blockIdx.z;
  const int cnt = cntp[e * CPAD];
  const int m0 = blockIdx.x * 256;
  if (m0 >= cnt) return;
  const int off = offp[e];
  const int n0 = blockIdx.y * 256;

  __shared__ __align__(16) unsigned short As[2][16384];
  __shared__ __align__(16) unsigned short Bs[2][16384];

  const int tid = threadIdx.x;
  const int w = tid >> 6, lane = tid & 63;
  const int r = lane & 15, kc = lane >> 4;
  const int wr = w >> 2, wc = w & 3;

  const unsigned short* srcA[2];
  const unsigned short* srcB[2];
#pragma unroll
  for (int i = 0; i < 2; ++i) {
    int g = 2 * w + i;
    int rowt = m0 + g * 16 + r;
    int rowc = (rowt < cnt) ? rowt : m0;
    srcA[i] = hsrc + (size_t)(off + rowc) * DDIM + kc * 8;
    int coln = n0 + g * 16 + r;
    srcB[i] = w2b + (size_t)e * DDIM * DDIM + (size_t)coln * DDIM + kc * 8;
  }

  f32x4 acc[8][4];
#pragma unroll
  for (int i = 0; i < 8; ++i)
#pragma unroll
    for (int j = 0; j < 4; ++j) acc[i][j] = (f32x4){0.f, 0.f, 0.f, 0.f};

  auto stage = [&](int buf, int k0) {
#pragma unroll
    for (int i = 0; i < 2; ++i) {
      int g = 2 * w + i;
#pragma unroll
      for (int ks = 0; ks < 2; ++ks) {
        GL2LDS(srcA[i] + k0 + ks * 32, &As[buf][g * 1024 + ks * 512 + lane * 8]);
        GL2LDS(srcB[i] + k0 + ks * 32, &Bs[buf][g * 1024 + ks * 512 + lane * 8]);
      }
    }
  };

  stage(0, 0);
  for (int s = 0; s < 16; ++s) {
    int buf = s & 1;
    __syncthreads();
    if (s + 1 < 16) stage(buf ^ 1, (s + 1) * 64);
#pragma unroll
    for (int ks = 0; ks < 2; ++ks) {
      bf16x8 af[8], bv[4];
#pragma unroll
      for (int i = 0; i < 8; ++i)
        af[i] = *(const bf16x8*)&As[buf][(wr * 8 + i) * 1024 + ks * 512 + lane * 8];
#pragma unroll
      for (int j = 0; j < 4; ++j)
        bv[j] = *(const bf16x8*)&Bs[buf][(wc * 4 + j) * 1024 + ks * 512 + lane * 8];
#pragma unroll
      for (int i = 0; i < 8; ++i)
#pragma unroll
        for (int j = 0; j < 4; ++j)
          acc[i][j] = __builtin_amdgcn_mfma_f32_16x16x32_bf16(af[i], bv[j], acc[i][j], 0, 0, 0);
    }
  }

  float bcol[4];
#pragma unroll
  for (int j = 0; j < 4; ++j) bcol[j] = b2[e * DDIM + n0 + wc * 64 + j * 16 + r];
#pragma unroll
  for (int i = 0; i < 8; ++i) {
#pragma unroll
    for (int q = 0; q < 4; ++q) {
      int grow = m0 + wr * 128 + i * 16 + kc * 4 + q;
      if (grow < cnt) {
        int tok = asgT[off + grow];
        float wgt = asgW[off + grow];
        float* orow = out + (size_t)tok * DDIM;
#pragma unroll
        for (int j = 0; j < 4; ++j) {
          int col = n0 + wc * 64 + j * 16 + r;
          atomicAdd(&orow[col], wgt * (acc[i][j][q] + bcol[j]));
        }
      }
    }
  }
}

// ---------------- launch ----------------
// ws layout (bytes):
//   0      cnt[8] padded x128B | 4096 off[8] | 8192 cur[8] padded
//   16384  tokE[NTOK] int32 (64KB) | +64K tokW float2 (128KB)
//   ...    asgT[2N] (128KB) | asgW[2N] (128KB)
//   1 MB   xb bf16 (32MB) | 33MB w1b (16MB) | 49MB w2b (16MB) | 65MB h (64MB)
extern "C" void kernel_launch(void* const* d_in, const int* in_sizes, int n_in,
                              void* d_out, int out_size, void* d_ws, size_t ws_size,
                              hipStream_t stream) {
  (void)in_sizes; (void)n_in; (void)ws_size;
  const float* x  = (const float*)d_in[0];
  const float* Wr = (const float*)d_in[1];
  const float* W1 = (const float*)d_in[2];
  const float* b1 = (const float*)d_in[3];
  const float* W2 = (const float*)d_in[4];
  const float* b2 = (const float*)d_in[5];
  float* out = (float*)d_out;

  char* ws = (char*)d_ws;
  int*    cnt  = (int*)(ws + 0);
  int*    off  = (int*)(ws + 4096);
  int*    cur  = (int*)(ws + 8192);
  int*    tokE = (int*)(ws + 16384);
  float2* tokW = (float2*)(ws + 16384 + 65536);
  int*    asgT = (int*)(ws + 16384 + 65536 + 131072);
  float*  asgW = (float*)(ws + 16384 + 65536 + 131072 + 131072);
  unsigned short* xb  = (unsigned short*)(ws + (size_t)(1u << 20));
  unsigned short* w1b = (unsigned short*)(ws + (size_t)33 * (1u << 20));
  unsigned short* w2b = (unsigned short*)(ws + (size_t)49 * (1u << 20));
  unsigned short* h   = (unsigned short*)(ws + (size_t)65 * (1u << 20));

  hipMemsetAsync(ws, 0, 16384, stream);                       // cnt + cur
  hipMemsetAsync(d_out, 0, (size_t)out_size * sizeof(float), stream);

  const int nW = NEXP * DDIM * DDIM;   // 8,388,608
  cast_k<<<(nW / 4) / 256, 256, 0, stream>>>(W1, w1b, nW / 4);
  cast_k<<<(nW / 4) / 256, 256, 0, stream>>>(W2, w2b, nW / 4);

  castx_router_k<<<NTOK, 256, 0, stream>>>(x, Wr, xb, tokE, tokW);
  hist_k<<<NTOK / 256, 256, 0, stream>>>(tokE, cnt);
  offsets_k<<<1, 64, 0, stream>>>(cnt, off);
  place_k<<<NTOK / 256, 256, 0, stream>>>(tokE, tokW, off, cur, asgT, asgW);

  // worst case one expert takes all NTOK tokens -> 64 m-tiles of 256
  dim3 ggrid(64, 4, NEXP);   // blocks past cnt[e] exit immediately
  gemm1_k<<<ggrid, 512, 0, stream>>>(xb, w1b, b1, cnt, off, asgT, h);
  gemm2_k<<<ggrid, 512, 0, stream>>>(h, w2b, b2, cnt, off, asgT, asgW, out);
}

// Round 6
// 701.253 us; speedup vs baseline: 1.6274x; 1.0202x over previous
//
#include <hip/hip_runtime.h>
#include <hip/hip_bf16.h>
#include <cstdint>
#include <cstddef>

#define NTOK 16384   // B*L = 4*4096
#define DDIM 1024
#define NEXP 8
#define CPAD 32      // counter padding: 32 ints = 128B per counter

typedef __attribute__((ext_vector_type(8))) short bf16x8;
typedef __attribute__((ext_vector_type(4))) float f32x4;

__device__ __forceinline__ unsigned short f2bf(float f) {
  union { float f; unsigned u; } c; c.f = f;
  unsigned r = (c.u + 0x7FFFu + ((c.u >> 16) & 1u)) >> 16;  // RNE
  return (unsigned short)r;
}

__device__ __forceinline__ float gelu_exact(float v) {
  return 0.5f * v * (1.0f + erff(v * 0.70710678118654752440f));
}

// direct global->LDS async copy, 16B per lane. LDS dest must be linear
// (wave-uniform base + lane*16); source address is per-lane.
#define GL2LDS(gp, lp) __builtin_amdgcn_global_load_lds( \
    (__attribute__((address_space(1))) void*)(gp),       \
    (__attribute__((address_space(3))) void*)(lp), 16, 0, 0)

// ---------------- cast fp32 -> bf16, 4 elems/thread (weights) ----------------
__global__ void cast_k(const float* __restrict__ src, unsigned short* __restrict__ dst, int n4) {
  int i = blockIdx.x * blockDim.x + threadIdx.x;
  if (i >= n4) return;
  float4 a = ((const float4*)src)[i];
  union { unsigned short s[4]; uint2 v; } o;
  o.s[0] = f2bf(a.x); o.s[1] = f2bf(a.y); o.s[2] = f2bf(a.z); o.s[3] = f2bf(a.w);
  ((uint2*)dst)[i] = o.v;
}

// ---------------- fused x-cast + router: one block per token, NO atomics ----------------
__global__ __launch_bounds__(256)
void castx_router_k(const float* __restrict__ x, const float* __restrict__ Wr,
                    unsigned short* __restrict__ xb, int* __restrict__ tokE,
                    float2* __restrict__ tokW) {
  const int t = blockIdx.x;
  const int tid = threadIdx.x;
  const int w = tid >> 6, lane = tid & 63;

  float4 xv = ((const float4*)x)[(size_t)t * 256 + tid];   // coalesced 16B/thread
  union { unsigned short s[4]; uint2 v; } o;
  o.s[0] = f2bf(xv.x); o.s[1] = f2bf(xv.y); o.s[2] = f2bf(xv.z); o.s[3] = f2bf(xv.w);
  ((uint2*)xb)[(size_t)t * 256 + tid] = o.v;

  const float4* Wr4 = (const float4*)Wr;                   // 32KB, L1-resident
  float p[NEXP];
#pragma unroll
  for (int e = 0; e < NEXP; ++e) {
    float4 wv = Wr4[e * 256 + tid];
    p[e] = xv.x * wv.x + xv.y * wv.y + xv.z * wv.z + xv.w * wv.w;
  }
#pragma unroll
  for (int e = 0; e < NEXP; ++e) {
    float v = p[e];
#pragma unroll
    for (int off = 32; off >= 1; off >>= 1) v += __shfl_xor(v, off, 64);
    p[e] = v;
  }
  __shared__ float red[4][NEXP];
  if (lane == 0) {
#pragma unroll
    for (int e = 0; e < NEXP; ++e) red[w][e] = p[e];
  }
  __syncthreads();
  if (tid == 0) {
    float s[NEXP];
#pragma unroll
    for (int e = 0; e < NEXP; ++e) s[e] = red[0][e] + red[1][e] + red[2][e] + red[3][e];
    int e1 = 0; float m1 = s[0];
#pragma unroll
    for (int e = 1; e < NEXP; ++e) if (s[e] > m1) { m1 = s[e]; e1 = e; }
    int e2 = -1; float m2 = -3.4e38f;
#pragma unroll
    for (int e = 0; e < NEXP; ++e) {
      if (e == e1) continue;
      if (s[e] > m2) { m2 = s[e]; e2 = e; }
    }
    float dd = expf(m2 - m1);                 // renormalized top-2 softmax
    tokE[t] = e1 | (e2 << 8);
    tokW[t] = make_float2(1.f / (1.f + dd), dd / (1.f + dd));
  }
}

// ---------------- histogram: ballot-aggregated, 8 atomics/block on padded lines ----------------
__global__ __launch_bounds__(256)
void hist_k(const int* __restrict__ tokE, int* __restrict__ cnt) {
  const int t = blockIdx.x * blockDim.x + threadIdx.x;
  const int w = threadIdx.x >> 6, lane = threadIdx.x & 63;
  const int pk = tokE[t];
  const int e1 = pk & 0xFF, e2 = (pk >> 8) & 0xFF;
  __shared__ int h[4][NEXP];
#pragma unroll
  for (int e = 0; e < NEXP; ++e) {
    int c = (int)__popcll(__ballot(e1 == e)) + (int)__popcll(__ballot(e2 == e));
    if (lane == 0) h[w][e] = c;
  }
  __syncthreads();
  if (threadIdx.x < NEXP) {
    int tot = h[0][threadIdx.x] + h[1][threadIdx.x] + h[2][threadIdx.x] + h[3][threadIdx.x];
    atomicAdd(&cnt[threadIdx.x * CPAD], tot);
  }
}

// ---------------- exclusive prefix over 8 padded counts ----------------
__global__ void offsets_k(const int* __restrict__ cnt, int* __restrict__ off) {
  if (threadIdx.x == 0) {
    int a = 0;
    for (int e = 0; e < NEXP; ++e) { off[e] = a; a += cnt[e * CPAD]; }
  }
}

// wave-aggregated bucket slot allocation on PADDED counters
__device__ __forceinline__ int bucket_slot(int* cur, int e_sel) {
  int lane = threadIdx.x & 63;
  int slot = 0;
#pragma unroll
  for (int e = 0; e < NEXP; ++e) {
    unsigned long long m = __ballot(e_sel == e);
    if (e_sel == e) {
      unsigned long long below = m & ((1ull << lane) - 1ull);
      int leader = __ffsll((long long)m) - 1;
      int base = 0;
      if (lane == leader) base = atomicAdd(&cur[e * CPAD], (int)__popcll(m));
      base = __shfl(base, leader, 64);
      slot = base + (int)__popcll(below);
    }
  }
  return slot;
}

__global__ __launch_bounds__(256)
void place_k(const int* __restrict__ tokE, const float2* __restrict__ tokW,
             const int* __restrict__ off, int* __restrict__ cur,
             int* __restrict__ asgT, float* __restrict__ asgW) {
  int t = blockIdx.x * blockDim.x + threadIdx.x;
  if (t >= NTOK) return;
  int pk = tokE[t];
  float2 w = tokW[t];
  int e1 = pk & 0xFF, e2 = (pk >> 8) & 0xFF;
  int p1 = off[e1] + bucket_slot(cur, e1);
  asgT[p1] = t; asgW[p1] = w.x;
  int p2 = off[e2] + bucket_slot(cur, e2);
  asgT[p2] = t; asgW[p2] = w.y;
}

// ========== 128x128 tile, BK=32, 4 waves, ring-3 LDS + counted vmcnt ==========
// LDS 3 x (8KB A + 8KB B) = 48KB -> 3 blocks/CU (12 waves). Each wave stages
// 4 x 1KB gl2lds per K-step; stages for steps t+1, t+2 stay in flight across the
// barrier (wait vmcnt(4), not 0). Fragment-major layout: group g (16 rows x 32k)
// = 1KB at g*1024B, lane*16B -> conflict-free ds_read_b128 AND linear gl2lds dest.
// Race check: at step t the wait leaves only stage t+1's 4 loads pending; stage
// t+2 overwrites the buffer consumed at t-1, whose ds_reads completed (lgkmcnt
// before MFMA) before each wave reached this step's barrier.

// ---------------- GEMM1: h = gelu(gather(x) @ W1[e]^T + b1[e]) ----------------
__global__ __launch_bounds__(256, 3)
void gemm1_k(const unsigned short* __restrict__ xb, const unsigned short* __restrict__ w1b,
             const float* __restrict__ b1, const int* __restrict__ cntp,
             const int* __restrict__ offp, const int* __restrict__ asgT,
             unsigned short* __restrict__ h) {
  const int e = blockIdx.z;
  const int cnt = cntp[e * CPAD];
  const int m0 = blockIdx.x * 128;
  if (m0 >= cnt) return;
  const int off = offp[e];
  const int n0 = blockIdx.y * 128;

  __shared__ __align__(16) unsigned short As[3][4096];
  __shared__ __align__(16) unsigned short Bs[3][4096];

  const int tid = threadIdx.x;
  const int w = tid >> 6, lane = tid & 63;
  const int r = lane & 15, kc = lane >> 4;
  const int wr = w >> 1, wc = w & 1;

  const unsigned short* srcA[2];
  const unsigned short* srcB[2];
#pragma unroll
  for (int i = 0; i < 2; ++i) {
    int g = w + i * 4;
    int rowt = m0 + g * 16 + r;
    int rowc = (rowt < cnt) ? rowt : m0;            // clamp (m0 is valid)
    int tok = asgT[off + rowc];
    srcA[i] = xb + (size_t)tok * DDIM + kc * 8;
    int coln = n0 + g * 16 + r;
    srcB[i] = w1b + (size_t)e * DDIM * DDIM + (size_t)coln * DDIM + kc * 8;
  }

  f32x4 acc[4][4];
#pragma unroll
  for (int i = 0; i < 4; ++i)
#pragma unroll
    for (int j = 0; j < 4; ++j) acc[i][j] = (f32x4){0.f, 0.f, 0.f, 0.f};

  auto stage = [&](int buf, int k0) {
#pragma unroll
    for (int i = 0; i < 2; ++i) {
      int g = w + i * 4;
      GL2LDS(srcA[i] + k0, &As[buf][g * 512 + lane * 8]);
      GL2LDS(srcB[i] + k0, &Bs[buf][g * 512 + lane * 8]);
    }
  };

  stage(0, 0);
  stage(1, 32);
  int bc = 0;                                  // buffer computed this step
  for (int t = 0; t < 32; ++t) {               // K = 1024 = 32 x 32
    if (t < 31) asm volatile("s_waitcnt vmcnt(4)" ::: "memory");
    else        asm volatile("s_waitcnt vmcnt(0)" ::: "memory");
    __builtin_amdgcn_sched_barrier(0);
    __builtin_amdgcn_s_barrier();
    __builtin_amdgcn_sched_barrier(0);
    if (t + 2 < 32) {
      int bs = bc + 2; if (bs >= 3) bs -= 3;
      stage(bs, (t + 2) * 32);
    }
    bf16x8 af[4], bv[4];
#pragma unroll
    for (int i = 0; i < 4; ++i) {
      af[i] = *(const bf16x8*)&As[bc][(wr * 4 + i) * 512 + lane * 8];
      bv[i] = *(const bf16x8*)&Bs[bc][(wc * 4 + i) * 512 + lane * 8];
    }
#pragma unroll
    for (int i = 0; i < 4; ++i)
#pragma unroll
      for (int j = 0; j < 4; ++j)
        acc[i][j] = __builtin_amdgcn_mfma_f32_16x16x32_bf16(af[i], bv[j], acc[i][j], 0, 0, 0);
    bc = (bc == 2) ? 0 : bc + 1;
  }

  float bcol[4];
#pragma unroll
  for (int j = 0; j < 4; ++j) bcol[j] = b1[e * DDIM + n0 + wc * 64 + j * 16 + r];
#pragma unroll
  for (int i = 0; i < 4; ++i) {
#pragma unroll
    for (int q = 0; q < 4; ++q) {
      int grow = m0 + wr * 64 + i * 16 + kc * 4 + q;   // C/D: row=(l>>4)*4+q, col=l&15
      if (grow < cnt) {
        size_t hrow = (size_t)(off + grow) * DDIM;
#pragma unroll
        for (int j = 0; j < 4; ++j) {
          int col = n0 + wc * 64 + j * 16 + r;
          h[hrow + col] = f2bf(gelu_exact(acc[i][j][q] + bcol[j]));
        }
      }
    }
  }
}

// ---------------- GEMM2: out[tok] += w * (h @ W2[e]^T + b2[e]) ----------------
__global__ __launch_bounds__(256, 3)
void gemm2_k(const unsigned short* __restrict__ hsrc, const unsigned short* __restrict__ w2b,
             const float* __restrict__ b2, const int* __restrict__ cntp,
             const int* __restrict__ offp, const int* __restrict__ asgT,
             const float* __restrict__ asgW, float* __restrict__ out) {
  const int e = blockIdx.z;
  const int cnt = cntp[e * CPAD];
  const int m0 = blockIdx.x * 128;
  if (m0 >= cnt) return;
  const int off = offp[e];
  const int n0 = blockIdx.y * 128;

  __shared__ __align__(16) unsigned short As[3][4096];
  __shared__ __align__(16) unsigned short Bs[3][4096];

  const int tid = threadIdx.x;
  const int w = tid >> 6, lane = tid & 63;
  const int r = lane & 15, kc = lane >> 4;
  const int wr = w >> 1, wc = w & 1;

  const unsigned short* srcA[2];
  const unsigned short* srcB[2];
#pragma unroll
  for (int i = 0; i < 2; ++i) {
    int g = w + i * 4;
    int rowt = m0 + g * 16 + r;
    int rowc = (rowt < cnt) ? rowt : m0;
    srcA[i] = hsrc + (size_t)(off + rowc) * DDIM + kc * 8;
    int coln = n0 + g * 16 + r;
    srcB[i] = w2b + (size_t)e * DDIM * DDIM + (size_t)coln * DDIM + kc * 8;
  }

  f32x4 acc[4][4];
#pragma unroll
  for (int i = 0; i < 4; ++i)
#pragma unroll
    for (int j = 0; j < 4; ++j) acc[i][j] = (f32x4){0.f, 0.f, 0.f, 0.f};

  auto stage = [&](int buf, int k0) {
#pragma unroll
    for (int i = 0; i < 2; ++i) {
      int g = w + i * 4;
      GL2LDS(srcA[i] + k0, &As[buf][g * 512 + lane * 8]);
      GL2LDS(srcB[i] + k0, &Bs[buf][g * 512 + lane * 8]);
    }
  };

  stage(0, 0);
  stage(1, 32);
  int bc = 0;
  for (int t = 0; t < 32; ++t) {
    if (t < 31) asm volatile("s_waitcnt vmcnt(4)" ::: "memory");
    else        asm volatile("s_waitcnt vmcnt(0)" ::: "memory");
    __builtin_amdgcn_sched_barrier(0);
    __builtin_amdgcn_s_barrier();
    __builtin_amdgcn_sched_barrier(0);
    if (t + 2 < 32) {
      int bs = bc + 2; if (bs >= 3) bs -= 3;
      stage(bs, (t + 2) * 32);
    }
    bf16x8 af[4], bv[4];
#pragma unroll
    for (int i = 0; i < 4; ++i) {
      af[i] = *(const bf16x8*)&As[bc][(wr * 4 + i) * 512 + lane * 8];
      bv[i] = *(const bf16x8*)&Bs[bc][(wc * 4 + i) * 512 + lane * 8];
    }
#pragma unroll
    for (int i = 0; i < 4; ++i)
#pragma unroll
      for (int j = 0; j < 4; ++j)
        acc[i][j] = __builtin_amdgcn_mfma_f32_16x16x32_bf16(af[i], bv[j], acc[i][j], 0, 0, 0);
    bc = (bc == 2) ? 0 : bc + 1;
  }

  float bcol[4];
#pragma unroll
  for (int j = 0; j < 4; ++j) bcol[j] = b2[e * DDIM + n0 + wc * 64 + j * 16 + r];
#pragma unroll
  for (int i = 0; i < 4; ++i) {
#pragma unroll
    for (int q = 0; q < 4; ++q) {
      int grow = m0 + wr * 64 + i * 16 + kc * 4 + q;
      if (grow < cnt) {
        int tok = asgT[off + grow];
        float wgt = asgW[off + grow];
        float* orow = out + (size_t)tok * DDIM;
#pragma unroll
        for (int j = 0; j < 4; ++j) {
          int col = n0 + wc * 64 + j * 16 + r;
          atomicAdd(&orow[col], wgt * (acc[i][j][q] + bcol[j]));
        }
      }
    }
  }
}

// ---------------- launch ----------------
// ws layout (bytes):
//   0      cnt[8] padded x128B | 4096 off[8] | 8192 cur[8] padded
//   16384  tokE[NTOK] int32 (64KB) | +64K tokW float2 (128KB)
//   ...    asgT[2N] (128KB) | asgW[2N] (128KB)
//   1 MB   xb bf16 (32MB) | 33MB w1b (16MB) | 49MB w2b (16MB) | 65MB h (64MB)
extern "C" void kernel_launch(void* const* d_in, const int* in_sizes, int n_in,
                              void* d_out, int out_size, void* d_ws, size_t ws_size,
                              hipStream_t stream) {
  (void)in_sizes; (void)n_in; (void)ws_size;
  const float* x  = (const float*)d_in[0];
  const float* Wr = (const float*)d_in[1];
  const float* W1 = (const float*)d_in[2];
  const float* b1 = (const float*)d_in[3];
  const float* W2 = (const float*)d_in[4];
  const float* b2 = (const float*)d_in[5];
  float* out = (float*)d_out;

  char* ws = (char*)d_ws;
  int*    cnt  = (int*)(ws + 0);
  int*    off  = (int*)(ws + 4096);
  int*    cur  = (int*)(ws + 8192);
  int*    tokE = (int*)(ws + 16384);
  float2* tokW = (float2*)(ws + 16384 + 65536);
  int*    asgT = (int*)(ws + 16384 + 65536 + 131072);
  float*  asgW = (float*)(ws + 16384 + 65536 + 131072 + 131072);
  unsigned short* xb  = (unsigned short*)(ws + (size_t)(1u << 20));
  unsigned short* w1b = (unsigned short*)(ws + (size_t)33 * (1u << 20));
  unsigned short* w2b = (unsigned short*)(ws + (size_t)49 * (1u << 20));
  unsigned short* h   = (unsigned short*)(ws + (size_t)65 * (1u << 20));

  hipMemsetAsync(ws, 0, 16384, stream);                       // cnt + cur
  hipMemsetAsync(d_out, 0, (size_t)out_size * sizeof(float), stream);

  const int nW = NEXP * DDIM * DDIM;   // 8,388,608
  cast_k<<<(nW / 4) / 256, 256, 0, stream>>>(W1, w1b, nW / 4);
  cast_k<<<(nW / 4) / 256, 256, 0, stream>>>(W2, w2b, nW / 4);

  castx_router_k<<<NTOK, 256, 0, stream>>>(x, Wr, xb, tokE, tokW);
  hist_k<<<NTOK / 256, 256, 0, stream>>>(tokE, cnt);
  offsets_k<<<1, 64, 0, stream>>>(cnt, off);
  place_k<<<NTOK / 256, 256, 0, stream>>>(tokE, tokW, off, cur, asgT, asgW);

  dim3 ggrid(128, 8, NEXP);   // worst-case tiles_m; blocks past cnt[e] exit
  gemm1_k<<<ggrid, 256, 0, stream>>>(xb, w1b, b1, cnt, off, asgT, h);
  gemm2_k<<<ggrid, 256, 0, stream>>>(h, w2b, b2, cnt, off, asgT, asgW, out);
}